// Round 7
// baseline (611.915 us; speedup 1.0000x reference)
//
#include <hip/hip_runtime.h>
#include <hip/hip_cooperative_groups.h>

namespace cg = cooperative_groups;

#define NQ     14
#define DIM    16384
#define NPAR   196
#define NCLS   10
#define NGATES 70

// ---------------- compile-time frame/gate tables (verified round 6) ----------------
// Stored state d[h] = s_ref[A(h)], A linear over GF(2)^14.
//  - CNOT chain:  s' = s o g, g(i)=i^(i>>1)  =>  A <- g^-1 o A
//  - rotation on ref bit bp: pair h <-> h^m[bp], role = parity(h & u[bp])
//  - physical relabel sigma (bits {12,13}<->{6,7}) => m,u <- sigma(m),sigma(u)
// Layout: h = p(2b,13:12) | w(3b,11:9) | k(3b,8:6) | lane(6b,5:0)
// Per round: phase-1 = gates with m avoiding p bits {12,13}; sigma (realized as
// the coalesced inter-phase global exchange); phase-2 = the rest, now local.
struct GateInfo { int m; int u; int slot; };
struct Tables { GateInfo g[NGATES]; int mu[NQ]; int swap_at[5]; bool valid; };

constexpr unsigned swapbits(unsigned v) {   // swap bits {6,7} <-> {12,13}
    return (v & ~0x30C0u) | ((v & 0xC0u) << 6) | ((v >> 6) & 0xC0u);
}

constexpr Tables make_tables() {
    Tables T{};
    T.valid = true;
    unsigned m[NQ] = {}, u[NQ] = {};
    for (int i = 0; i < NQ; ++i) { m[i] = 1u << i; u[i] = 1u << i; }
    int gi = 0;
    for (int r = 0; r < 5; ++r) {
        bool done[NQ] = {};
        for (int q = 0; q < NQ; ++q) {            // phase 1: m avoids bits 12,13
            int bp = 13 - q;
            if ((m[bp] & 0x3000u) == 0u) {
                T.g[gi].m = (int)m[bp]; T.g[gi].u = (int)u[bp];
                T.g[gi].slot = r * 14 + q;
                done[q] = true; ++gi;
            }
        }
        T.swap_at[r] = gi;
        if (r > 0 && T.swap_at[r] <= T.swap_at[r - 1]) T.valid = false;
        for (int i = 0; i < NQ; ++i) { m[i] = swapbits(m[i]); u[i] = swapbits(u[i]); }
        for (int q = 0; q < NQ; ++q) {            // phase 2: local after sigma
            if (!done[q]) {
                int bp = 13 - q;
                if ((m[bp] & 0x3000u) != 0u) T.valid = false;
                T.g[gi].m = (int)m[bp]; T.g[gi].u = (int)u[bp];
                T.g[gi].slot = r * 14 + q;
                ++gi;
            }
        }
        if (r < 4) {                              // CNOT chain retabulation
            for (int bp = 13; bp >= 1; --bp) m[bp] ^= m[bp - 1];
            unsigned acc = 0;
            for (int bp = 13; bp >= 0; --bp) { acc ^= u[bp]; u[bp] = acc; }
        }
    }
    if (gi != NGATES) T.valid = false;
    for (int q = 0; q < NQ; ++q) T.mu[q] = (int)u[13 - q];
    return T;
}
constexpr Tables TAB = make_tables();
static_assert(TAB.valid, "gate schedule construction failed");

constexpr int seg_lo(int s) { return s == 0 ? 0 : TAB.swap_at[s - 1]; }
constexpr int seg_hi(int s) { return s < 5 ? TAB.swap_at[s] : NGATES; }

// Apply gates [seg_lo(SEG), seg_hi(SEG)) to the 8 register amps.
// All masks compile-time (fully unrolled); mw-path barriers are uniform.
template<int SEG>
__device__ __forceinline__ void do_gates(float (&ar)[8], float (&ai)[8],
    const float (*uc)[8], float* lds_r, float* lds_i, int tid, int hbase)
{
    constexpr int LO = seg_lo(SEG);
    constexpr int HI = seg_hi(SEG);
    #pragma unroll
    for (int g = LO; g < HI; ++g) {
        const int m = TAB.g[g].m, u = TAB.g[g].u;
        const float4 c0 = *(const float4*)&uc[g][0];  // {00r,00i,01r,01i}
        const float4 c1 = *(const float4*)&uc[g][4];  // {10r,10i,11r,11i}
        const bool rb = (__popc(hbase & u) & 1) != 0;
        const float D0r = rb ? c1.z : c0.x, D0i = rb ? c1.w : c0.y;
        const float O0r = rb ? c1.x : c0.z, O0i = rb ? c1.y : c0.w;
        const float D1r = rb ? c0.x : c1.z, D1i = rb ? c0.y : c1.w;
        const float O1r = rb ? c0.z : c1.x, O1i = rb ? c0.w : c1.y;

        const int ml = m & 63;            // lane part
        const int mk = (m >> 6) & 7;      // reg part
        const int mw = (m >> 9) & 7;      // wave part
        float pr[8], pim[8];
        if (mw == 0 && ml == 0) {
            #pragma unroll
            for (int k = 0; k < 8; ++k) { pr[k] = ar[k ^ mk]; pim[k] = ai[k ^ mk]; }
        } else if (mw == 0) {
            #pragma unroll
            for (int k = 0; k < 8; ++k) {
                pr[k]  = __shfl_xor(ar[k ^ mk], ml, 64);
                pim[k] = __shfl_xor(ai[k ^ mk], ml, 64);
            }
        } else {
            const int tm = (mw << 6) | ml;
            __syncthreads();   // WAR: prior readers of lds done
            #pragma unroll
            for (int k = 0; k < 8; ++k) {
                lds_r[k * 512 + tid] = ar[k];
                lds_i[k * 512 + tid] = ai[k];
            }
            __syncthreads();
            #pragma unroll
            for (int k = 0; k < 8; ++k) {
                pr[k]  = lds_r[(k ^ mk) * 512 + (tid ^ tm)];
                pim[k] = lds_i[(k ^ mk) * 512 + (tid ^ tm)];
            }
        }
        const int ku = (u >> 6) & 7;
        #pragma unroll
        for (int k = 0; k < 8; ++k) {
            const int cls = __popc(k & ku) & 1;   // compile-time per k
            const float Dr = cls ? D1r : D0r, Di = cls ? D1i : D0i;
            const float Or = cls ? O1r : O0r, Oi = cls ? O1i : O0i;
            float nr = Dr * ar[k] - Di * ai[k] + Or * pr[k] - Oi * pim[k];
            float ni = Dr * ai[k] + Di * ar[k] + Or * pim[k] + Oi * pr[k];
            ar[k] = nr; ai[k] = ni;
        }
    }
}

// ============ single cooperative kernel: 256 blocks x 512 threads ============
// h = p<<12 | w<<9 | k<<6 | l ;  e = blk>>2, p = blk&3, w = tid>>6, l = tid&63
// Boundary sigma ({12,13}<->{6,7}): writer amp (p,w,k,l) -> buffer slot
//   (k&3)<<12 | w<<9 | (k>>2)<<8 | p<<6 | l   (reader-linear; both sides coalesced)
__global__ void __launch_bounds__(512, 2)
qvc_coop(const float* __restrict__ x, const float* __restrict__ W,
         const float* __restrict__ bias, float2* __restrict__ bufA,
         float2* __restrict__ bufB, float* __restrict__ part,
         float* __restrict__ out)
{
    __shared__ __align__(16) float uc[NGATES][8];
    __shared__ float lds_r[8 * 512];
    __shared__ float lds_i[8 * 512];
    __shared__ float red[8][NQ];

    cg::grid_group grid = cg::this_grid();

    const int blk = blockIdx.x;
    const int e = blk >> 2, p = blk & 3;
    const int tid = threadIdx.x;
    const int w = tid >> 6, l = tid & 63;
    const int hbase = (p << 12) | (w << 9) | l;   // h minus the k bits
    const float* xb = x + e * NPAR;

    // ---- all 70 gate-coefficient sets, one gate per thread ----
    if (tid < NGATES) {
        const int slot = TAB.g[tid].slot;
        const int layer = slot / 14, q = slot % 14;
        const int pidx = (layer < 4) ? layer * 42 + q * 3 : 168 + q * 2;
        float a1 = 0.5f * xb[pidx], a2 = 0.5f * xb[pidx + 1];
        float s1, c1, s2, c2;
        sincosf(a1, &s1, &c1);
        sincosf(a2, &s2, &c2);
        float A00r =  c2 * c1, A00i =  s2 * s1;
        float A01r = -s2 * c1, A01i = -c2 * s1;
        float A10r =  s2 * c1, A10i = -c2 * s1;
        float A11r =  c2 * c1, A11i = -s2 * s1;
        float U0, U1, U2, U3, U4, U5, U6, U7;
        if (layer < 4) {
            float a3 = 0.5f * xb[pidx + 2]; float s3, c3; sincosf(a3, &s3, &c3);
            U0 = c3 * A00r + s3 * A00i; U1 = c3 * A00i - s3 * A00r;
            U2 = c3 * A01r + s3 * A01i; U3 = c3 * A01i - s3 * A01r;
            U4 = c3 * A10r - s3 * A10i; U5 = c3 * A10i + s3 * A10r;
            U6 = c3 * A11r - s3 * A11i; U7 = c3 * A11i + s3 * A11r;
        } else {
            U0 = A00r; U1 = A00i; U2 = A01r; U3 = A01i;
            U4 = A10r; U5 = A10i; U6 = A11r; U7 = A11i;
        }
        uc[tid][0] = U0; uc[tid][1] = U1; uc[tid][2] = U2; uc[tid][3] = U3;
        uc[tid][4] = U4; uc[tid][5] = U5; uc[tid][6] = U6; uc[tid][7] = U7;
    }

    float ar[8], ai[8];
    #pragma unroll
    for (int k = 0; k < 8; ++k) { ar[k] = 0.0f; ai[k] = 0.0f; }
    if (p == 0 && tid == 0) ar[0] = 1.0f;
    __syncthreads();

    // σ exchange helpers (writer-permuted store, linear load)
    auto store_sigma = [&](float2* buf) {
        #pragma unroll
        for (int k = 0; k < 8; ++k) {
            const int idx = (e << 14) | ((k & 3) << 12) | (w << 9) |
                            ((k >> 2) << 8) | (p << 6) | l;
            buf[idx] = make_float2(ar[k], ai[k]);
        }
    };
    auto load_linear = [&](const float2* buf) {
        #pragma unroll
        for (int k = 0; k < 8; ++k) {
            float2 v = buf[(e << 14) | hbase | (k << 6)];
            ar[k] = v.x; ai[k] = v.y;
        }
    };

    do_gates<0>(ar, ai, uc, lds_r, lds_i, tid, hbase);
    store_sigma(bufA);
    __threadfence();
    grid.sync();

    load_linear(bufA);
    do_gates<1>(ar, ai, uc, lds_r, lds_i, tid, hbase);
    store_sigma(bufB);
    __threadfence();
    grid.sync();

    load_linear(bufB);
    do_gates<2>(ar, ai, uc, lds_r, lds_i, tid, hbase);
    store_sigma(bufA);
    __threadfence();
    grid.sync();

    load_linear(bufA);
    do_gates<3>(ar, ai, uc, lds_r, lds_i, tid, hbase);
    store_sigma(bufB);
    __threadfence();
    grid.sync();

    load_linear(bufB);
    do_gates<4>(ar, ai, uc, lds_r, lds_i, tid, hbase);
    store_sigma(bufA);
    __threadfence();
    grid.sync();

    load_linear(bufA);
    do_gates<5>(ar, ai, uc, lds_r, lds_i, tid, hbase);

    // ---- measurement partials: E_q = sum |amp|^2 * (-1)^parity(h & mu[q]) ----
    {
        float eq[NQ];
        #pragma unroll
        for (int q = 0; q < NQ; ++q) eq[q] = 0.0f;
        #pragma unroll
        for (int k = 0; k < 8; ++k) {
            float p2 = ar[k] * ar[k] + ai[k] * ai[k];
            #pragma unroll
            for (int q = 0; q < NQ; ++q) {
                if (__popc(k & ((TAB.mu[q] >> 6) & 7)) & 1) eq[q] -= p2; else eq[q] += p2;
            }
        }
        #pragma unroll
        for (int q = 0; q < NQ; ++q) {
            float v = (__popc(hbase & TAB.mu[q]) & 1) ? -eq[q] : eq[q];
            #pragma unroll
            for (int off = 32; off > 0; off >>= 1) v += __shfl_down(v, off, 64);
            eq[q] = v;
        }
        if (l == 0) {
            #pragma unroll
            for (int q = 0; q < NQ; ++q) red[w][q] = eq[q];
        }
        __syncthreads();
        if (tid < NQ) {
            float s = 0.0f;
            #pragma unroll
            for (int ww = 0; ww < 8; ++ww) s += red[ww][tid];
            part[(e * 4 + p) * NQ + tid] = s;
        }
    }
    __threadfence();
    grid.sync();

    // ---- head: blocks 0..63, one element each ----
    if (blk < 64 && tid < NCLS) {
        const int e2 = blk, c = tid;
        float acc = bias[c];
        const float* pe = part + e2 * 4 * NQ;
        #pragma unroll
        for (int q = 0; q < NQ; ++q) {
            float eqv = pe[q] + pe[NQ + q] + pe[2 * NQ + q] + pe[3 * NQ + q];
            acc += W[c * NQ + q] * eqv;
        }
        out[e2 * NCLS + c] = acc;
    }
}

extern "C" void kernel_launch(void* const* d_in, const int* in_sizes, int n_in,
                              void* d_out, int out_size, void* d_ws, size_t ws_size,
                              hipStream_t stream)
{
    const float* x    = (const float*)d_in[0];   // (64, 196)
    const float* W    = (const float*)d_in[1];   // (10, 14)
    const float* bias = (const float*)d_in[2];   // (10,)
    float*       out  = (float*)d_out;           // (64, 10)

    const size_t state_elems = (size_t)64 * DIM;          // float2 each
    float2* bufA = (float2*)d_ws;
    float2* bufB = bufA + state_elems;
    float*  part = (float*)(bufB + state_elems);
    (void)ws_size;  // observed 268 MB >> 16.03 MB needed

    void* args[] = { (void*)&x, (void*)&W, (void*)&bias,
                     (void*)&bufA, (void*)&bufB, (void*)&part, (void*)&out };
    hipLaunchCooperativeKernel((void*)qvc_coop, dim3(256), dim3(512),
                               args, 0, stream);
}

// Round 8
// 522.331 us; speedup vs baseline: 1.1715x; 1.1715x over previous
//
#include <hip/hip_runtime.h>

#define NQ     14
#define DIM    16384
#define NPAR   196
#define NCLS   10
#define NGATES 70
#define NBLK   256

// ---------------- compile-time frame/gate tables (verified rounds 6-7) ----------------
// Stored state d[h] = s_ref[A(h)], A linear over GF(2)^14.
//  - CNOT chain:  s' = s o g, g(i)=i^(i>>1)  =>  A <- g^-1 o A
//  - rotation on ref bit bp: pair h <-> h^m[bp], role = parity(h & u[bp])
//  - physical relabel sigma (bits {12,13}<->{6,7}) => m,u <- sigma(m),sigma(u)
// Layout: h = p(2b,13:12) | w(3b,11:9) | k(3b,8:6) | lane(6b,5:0)
// Per round: phase-1 = gates with m avoiding p bits {12,13}; sigma (realized as
// the coalesced inter-phase global exchange); phase-2 = the rest, now local.
struct GateInfo { int m; int u; int slot; };
struct Tables { GateInfo g[NGATES]; int mu[NQ]; int swap_at[5]; bool valid; };

constexpr unsigned swapbits(unsigned v) {   // swap bits {6,7} <-> {12,13}
    return (v & ~0x30C0u) | ((v & 0xC0u) << 6) | ((v >> 6) & 0xC0u);
}

constexpr Tables make_tables() {
    Tables T{};
    T.valid = true;
    unsigned m[NQ] = {}, u[NQ] = {};
    for (int i = 0; i < NQ; ++i) { m[i] = 1u << i; u[i] = 1u << i; }
    int gi = 0;
    for (int r = 0; r < 5; ++r) {
        bool done[NQ] = {};
        for (int q = 0; q < NQ; ++q) {            // phase 1: m avoids bits 12,13
            int bp = 13 - q;
            if ((m[bp] & 0x3000u) == 0u) {
                T.g[gi].m = (int)m[bp]; T.g[gi].u = (int)u[bp];
                T.g[gi].slot = r * 14 + q;
                done[q] = true; ++gi;
            }
        }
        T.swap_at[r] = gi;
        if (r > 0 && T.swap_at[r] <= T.swap_at[r - 1]) T.valid = false;
        for (int i = 0; i < NQ; ++i) { m[i] = swapbits(m[i]); u[i] = swapbits(u[i]); }
        for (int q = 0; q < NQ; ++q) {            // phase 2: local after sigma
            if (!done[q]) {
                int bp = 13 - q;
                if ((m[bp] & 0x3000u) != 0u) T.valid = false;
                T.g[gi].m = (int)m[bp]; T.g[gi].u = (int)u[bp];
                T.g[gi].slot = r * 14 + q;
                ++gi;
            }
        }
        if (r < 4) {                              // CNOT chain retabulation
            for (int bp = 13; bp >= 1; --bp) m[bp] ^= m[bp - 1];
            unsigned acc = 0;
            for (int bp = 13; bp >= 0; --bp) { acc ^= u[bp]; u[bp] = acc; }
        }
    }
    if (gi != NGATES) T.valid = false;
    for (int q = 0; q < NQ; ++q) T.mu[q] = (int)u[13 - q];
    return T;
}
constexpr Tables TAB = make_tables();
static_assert(TAB.valid, "gate schedule construction failed");

constexpr int seg_lo(int s) { return s == 0 ? 0 : TAB.swap_at[s - 1]; }
constexpr int seg_hi(int s) { return s < 5 ? TAB.swap_at[s] : NGATES; }

// ---------------- fast grid barrier (replaces cg::grid.sync, ~90us/sync) ----------------
// cnt/sense in d_ws, zeroed by captured hipMemsetAsync each call.
// Monotonic sense (ep = 1,2,...). Release on sense store orders the cnt reset.
// __threadfence (agent scope) before/after provides cross-XCD data visibility.
__device__ __forceinline__ void gbar(unsigned* cnt, unsigned* sense, unsigned ep) {
    __threadfence();          // release this thread's prior stores (L2 wb)
    __syncthreads();
    if (threadIdx.x == 0) {
        unsigned old = __hip_atomic_fetch_add(cnt, 1u, __ATOMIC_RELAXED,
                                              __HIP_MEMORY_SCOPE_AGENT);
        if (old == NBLK - 1u) {
            __hip_atomic_store(cnt, 0u, __ATOMIC_RELAXED, __HIP_MEMORY_SCOPE_AGENT);
            __hip_atomic_store(sense, ep, __ATOMIC_RELEASE, __HIP_MEMORY_SCOPE_AGENT);
        } else {
            while (__hip_atomic_load(sense, __ATOMIC_RELAXED,
                                     __HIP_MEMORY_SCOPE_AGENT) < ep)
                __builtin_amdgcn_s_sleep(2);
        }
    }
    __syncthreads();
    __threadfence();          // acquire: invalidate stale L1/L2 before reads
}

// Apply gates [seg_lo(SEG), seg_hi(SEG)) to the 8 register amps.
template<int SEG>
__device__ __forceinline__ void do_gates(float (&ar)[8], float (&ai)[8],
    const float (*uc)[8], float* lds_r, float* lds_i, int tid, int hbase)
{
    constexpr int LO = seg_lo(SEG);
    constexpr int HI = seg_hi(SEG);
    #pragma unroll
    for (int g = LO; g < HI; ++g) {
        const int m = TAB.g[g].m, u = TAB.g[g].u;
        const float4 c0 = *(const float4*)&uc[g][0];  // {00r,00i,01r,01i}
        const float4 c1 = *(const float4*)&uc[g][4];  // {10r,10i,11r,11i}
        const bool rb = (__popc(hbase & u) & 1) != 0;
        const float D0r = rb ? c1.z : c0.x, D0i = rb ? c1.w : c0.y;
        const float O0r = rb ? c1.x : c0.z, O0i = rb ? c1.y : c0.w;
        const float D1r = rb ? c0.x : c1.z, D1i = rb ? c0.y : c1.w;
        const float O1r = rb ? c0.z : c1.x, O1i = rb ? c0.w : c1.y;

        const int ml = m & 63;            // lane part
        const int mk = (m >> 6) & 7;      // reg part
        const int mw = (m >> 9) & 7;      // wave part
        float pr[8], pim[8];
        if (mw == 0 && ml == 0) {
            #pragma unroll
            for (int k = 0; k < 8; ++k) { pr[k] = ar[k ^ mk]; pim[k] = ai[k ^ mk]; }
        } else if (mw == 0) {
            #pragma unroll
            for (int k = 0; k < 8; ++k) {
                pr[k]  = __shfl_xor(ar[k ^ mk], ml, 64);
                pim[k] = __shfl_xor(ai[k ^ mk], ml, 64);
            }
        } else {
            const int tm = (mw << 6) | ml;
            __syncthreads();   // WAR: prior readers of lds done
            #pragma unroll
            for (int k = 0; k < 8; ++k) {
                lds_r[k * 512 + tid] = ar[k];
                lds_i[k * 512 + tid] = ai[k];
            }
            __syncthreads();
            #pragma unroll
            for (int k = 0; k < 8; ++k) {
                pr[k]  = lds_r[(k ^ mk) * 512 + (tid ^ tm)];
                pim[k] = lds_i[(k ^ mk) * 512 + (tid ^ tm)];
            }
        }
        const int ku = (u >> 6) & 7;
        #pragma unroll
        for (int k = 0; k < 8; ++k) {
            const int cls = __popc(k & ku) & 1;   // compile-time per k
            const float Dr = cls ? D1r : D0r, Di = cls ? D1i : D0i;
            const float Or = cls ? O1r : O0r, Oi = cls ? O1i : O0i;
            float nr = Dr * ar[k] - Di * ai[k] + Or * pr[k] - Oi * pim[k];
            float ni = Dr * ai[k] + Di * ar[k] + Or * pim[k] + Oi * pr[k];
            ar[k] = nr; ai[k] = ni;
        }
    }
}

// ============ single launch: 256 blocks x 512 threads, custom grid barrier ============
// h = p<<12 | w<<9 | k<<6 | l.  XCD swizzle: all 4 parts of an element share an XCD
// (blk%8 = XCD under round-robin dispatch; perf heuristic only, never correctness).
// Boundary sigma ({12,13}<->{6,7}): writer amp (p,w,k,l) -> buffer slot
//   (k&3)<<12 | w<<9 | (k>>2)<<8 | p<<6 | l   (reader-linear; both sides coalesced)
__global__ void __launch_bounds__(512, 2)
qvc_persist(const float* __restrict__ x, const float* __restrict__ W,
            const float* __restrict__ bias, float2* __restrict__ bufA,
            float2* __restrict__ bufB, float* __restrict__ part,
            float* __restrict__ out, unsigned* __restrict__ bar)
{
    __shared__ __align__(16) float uc[NGATES][8];
    __shared__ float lds_r[8 * 512];
    __shared__ float lds_i[8 * 512];
    __shared__ float red[8][NQ];

    unsigned* cnt   = bar;
    unsigned* sense = bar + 32;   // separate cache line

    const int blk = blockIdx.x;
    const int xcd = blk & 7, slot = blk >> 3;
    const int e = xcd * 8 + (slot >> 2), p = slot & 3;   // 4 parts of e on one XCD
    const int tid = threadIdx.x;
    const int w = tid >> 6, l = tid & 63;
    const int hbase = (p << 12) | (w << 9) | l;   // h minus the k bits
    const float* xb = x + e * NPAR;

    // ---- all 70 gate-coefficient sets, one gate per thread ----
    if (tid < NGATES) {
        const int gslot = TAB.g[tid].slot;
        const int layer = gslot / 14, q = gslot % 14;
        const int pidx = (layer < 4) ? layer * 42 + q * 3 : 168 + q * 2;
        float a1 = 0.5f * xb[pidx], a2 = 0.5f * xb[pidx + 1];
        float s1, c1, s2, c2;
        sincosf(a1, &s1, &c1);
        sincosf(a2, &s2, &c2);
        float A00r =  c2 * c1, A00i =  s2 * s1;
        float A01r = -s2 * c1, A01i = -c2 * s1;
        float A10r =  s2 * c1, A10i = -c2 * s1;
        float A11r =  c2 * c1, A11i = -s2 * s1;
        float U0, U1, U2, U3, U4, U5, U6, U7;
        if (layer < 4) {
            float a3 = 0.5f * xb[pidx + 2]; float s3, c3; sincosf(a3, &s3, &c3);
            U0 = c3 * A00r + s3 * A00i; U1 = c3 * A00i - s3 * A00r;
            U2 = c3 * A01r + s3 * A01i; U3 = c3 * A01i - s3 * A01r;
            U4 = c3 * A10r - s3 * A10i; U5 = c3 * A10i + s3 * A10r;
            U6 = c3 * A11r - s3 * A11i; U7 = c3 * A11i + s3 * A11r;
        } else {
            U0 = A00r; U1 = A00i; U2 = A01r; U3 = A01i;
            U4 = A10r; U5 = A10i; U6 = A11r; U7 = A11i;
        }
        uc[tid][0] = U0; uc[tid][1] = U1; uc[tid][2] = U2; uc[tid][3] = U3;
        uc[tid][4] = U4; uc[tid][5] = U5; uc[tid][6] = U6; uc[tid][7] = U7;
    }

    float ar[8], ai[8];
    #pragma unroll
    for (int k = 0; k < 8; ++k) { ar[k] = 0.0f; ai[k] = 0.0f; }
    if (p == 0 && tid == 0) ar[0] = 1.0f;
    __syncthreads();

    auto store_sigma = [&](float2* buf) {
        #pragma unroll
        for (int k = 0; k < 8; ++k) {
            const int idx = (e << 14) | ((k & 3) << 12) | (w << 9) |
                            ((k >> 2) << 8) | (p << 6) | l;
            buf[idx] = make_float2(ar[k], ai[k]);
        }
    };
    auto load_linear = [&](const float2* buf) {
        #pragma unroll
        for (int k = 0; k < 8; ++k) {
            float2 v = buf[(e << 14) | hbase | (k << 6)];
            ar[k] = v.x; ai[k] = v.y;
        }
    };

    do_gates<0>(ar, ai, uc, lds_r, lds_i, tid, hbase);
    store_sigma(bufA);
    gbar(cnt, sense, 1);

    load_linear(bufA);
    do_gates<1>(ar, ai, uc, lds_r, lds_i, tid, hbase);
    store_sigma(bufB);
    gbar(cnt, sense, 2);

    load_linear(bufB);
    do_gates<2>(ar, ai, uc, lds_r, lds_i, tid, hbase);
    store_sigma(bufA);
    gbar(cnt, sense, 3);

    load_linear(bufA);
    do_gates<3>(ar, ai, uc, lds_r, lds_i, tid, hbase);
    store_sigma(bufB);
    gbar(cnt, sense, 4);

    load_linear(bufB);
    do_gates<4>(ar, ai, uc, lds_r, lds_i, tid, hbase);
    store_sigma(bufA);
    gbar(cnt, sense, 5);

    load_linear(bufA);
    do_gates<5>(ar, ai, uc, lds_r, lds_i, tid, hbase);

    // ---- measurement partials: E_q = sum |amp|^2 * (-1)^parity(h & mu[q]) ----
    {
        float eq[NQ];
        #pragma unroll
        for (int q = 0; q < NQ; ++q) eq[q] = 0.0f;
        #pragma unroll
        for (int k = 0; k < 8; ++k) {
            float p2 = ar[k] * ar[k] + ai[k] * ai[k];
            #pragma unroll
            for (int q = 0; q < NQ; ++q) {
                if (__popc(k & ((TAB.mu[q] >> 6) & 7)) & 1) eq[q] -= p2; else eq[q] += p2;
            }
        }
        #pragma unroll
        for (int q = 0; q < NQ; ++q) {
            float v = (__popc(hbase & TAB.mu[q]) & 1) ? -eq[q] : eq[q];
            #pragma unroll
            for (int off = 32; off > 0; off >>= 1) v += __shfl_down(v, off, 64);
            eq[q] = v;
        }
        if (l == 0) {
            #pragma unroll
            for (int q = 0; q < NQ; ++q) red[w][q] = eq[q];
        }
        __syncthreads();
        if (tid < NQ) {
            float s = 0.0f;
            #pragma unroll
            for (int ww = 0; ww < 8; ++ww) s += red[ww][tid];
            part[(e * 4 + p) * NQ + tid] = s;
        }
    }
    gbar(cnt, sense, 6);

    // ---- head: blocks 0..63, one element each ----
    if (blk < 64 && tid < NCLS) {
        const int e2 = blk, c = tid;
        float acc = bias[c];
        const float* pe = part + e2 * 4 * NQ;
        #pragma unroll
        for (int q = 0; q < NQ; ++q) {
            float eqv = pe[q] + pe[NQ + q] + pe[2 * NQ + q] + pe[3 * NQ + q];
            acc += W[c * NQ + q] * eqv;
        }
        out[e2 * NCLS + c] = acc;
    }
}

extern "C" void kernel_launch(void* const* d_in, const int* in_sizes, int n_in,
                              void* d_out, int out_size, void* d_ws, size_t ws_size,
                              hipStream_t stream)
{
    const float* x    = (const float*)d_in[0];   // (64, 196)
    const float* W    = (const float*)d_in[1];   // (10, 14)
    const float* bias = (const float*)d_in[2];   // (10,)
    float*       out  = (float*)d_out;           // (64, 10)

    const size_t state_elems = (size_t)64 * DIM;          // float2 each
    float2*   bufA = (float2*)d_ws;
    float2*   bufB = bufA + state_elems;
    float*    part = (float*)(bufB + state_elems);        // 64*4*14 floats
    unsigned* bar  = (unsigned*)((char*)d_ws + 2 * state_elems * sizeof(float2) + 16384);
    (void)ws_size;  // observed 268 MB >> ~16.1 MB needed

    // zero barrier state every call (captured as a graph memset node; poison-safe)
    hipMemsetAsync(bar, 0, 256, stream);

    void* args[] = { (void*)&x, (void*)&W, (void*)&bias,
                     (void*)&bufA, (void*)&bufB, (void*)&part,
                     (void*)&out, (void*)&bar };
    hipLaunchCooperativeKernel((void*)qvc_persist, dim3(NBLK), dim3(512),
                               args, 0, stream);
}

// Round 9
// 121.161 us; speedup vs baseline: 5.0504x; 4.3111x over previous
//
#include <hip/hip_runtime.h>

#define NQ     14
#define DIM    16384
#define NPAR   196
#define NCLS   10
#define NGATES 70
#define NBLK   256

// ---------------- compile-time frame/gate tables (verified rounds 6-8) ----------------
// Stored state d[h] = s_ref[A(h)], A linear over GF(2)^14.
//  - CNOT chain:  s' = s o g, g(i)=i^(i>>1)  =>  A <- g^-1 o A
//  - rotation on ref bit bp: pair h <-> h^m[bp], role = parity(h & u[bp])
//  - physical relabel sigma (bits {12,13}<->{6,7}) => m,u <- sigma(m),sigma(u)
// Layout: h = p(2b,13:12) | w(3b,11:9) | k(3b,8:6) | lane(6b,5:0)
// Per round: phase-1 = gates with m avoiding p bits {12,13}; sigma (realized as
// the coherent inter-phase global exchange); phase-2 = the rest, now local.
struct GateInfo { int m; int u; int slot; };
struct Tables { GateInfo g[NGATES]; int mu[NQ]; int swap_at[5]; bool valid; };

constexpr unsigned swapbits(unsigned v) {   // swap bits {6,7} <-> {12,13}
    return (v & ~0x30C0u) | ((v & 0xC0u) << 6) | ((v >> 6) & 0xC0u);
}

constexpr Tables make_tables() {
    Tables T{};
    T.valid = true;
    unsigned m[NQ] = {}, u[NQ] = {};
    for (int i = 0; i < NQ; ++i) { m[i] = 1u << i; u[i] = 1u << i; }
    int gi = 0;
    for (int r = 0; r < 5; ++r) {
        bool done[NQ] = {};
        for (int q = 0; q < NQ; ++q) {            // phase 1: m avoids bits 12,13
            int bp = 13 - q;
            if ((m[bp] & 0x3000u) == 0u) {
                T.g[gi].m = (int)m[bp]; T.g[gi].u = (int)u[bp];
                T.g[gi].slot = r * 14 + q;
                done[q] = true; ++gi;
            }
        }
        T.swap_at[r] = gi;
        if (r > 0 && T.swap_at[r] <= T.swap_at[r - 1]) T.valid = false;
        for (int i = 0; i < NQ; ++i) { m[i] = swapbits(m[i]); u[i] = swapbits(u[i]); }
        for (int q = 0; q < NQ; ++q) {            // phase 2: local after sigma
            if (!done[q]) {
                int bp = 13 - q;
                if ((m[bp] & 0x3000u) != 0u) T.valid = false;
                T.g[gi].m = (int)m[bp]; T.g[gi].u = (int)u[bp];
                T.g[gi].slot = r * 14 + q;
                ++gi;
            }
        }
        if (r < 4) {                              // CNOT chain retabulation
            for (int bp = 13; bp >= 1; --bp) m[bp] ^= m[bp - 1];
            unsigned acc = 0;
            for (int bp = 13; bp >= 0; --bp) { acc ^= u[bp]; u[bp] = acc; }
        }
    }
    if (gi != NGATES) T.valid = false;
    for (int q = 0; q < NQ; ++q) T.mu[q] = (int)u[13 - q];
    return T;
}
constexpr Tables TAB = make_tables();
static_assert(TAB.valid, "gate schedule construction failed");

constexpr int seg_lo(int s) { return s == 0 ? 0 : TAB.swap_at[s - 1]; }
constexpr int seg_hi(int s) { return s < 5 ? TAB.swap_at[s] : NGATES; }

// ---------------- fence-free grid barrier ----------------
// Round 7/8 lesson: per-wave agent-scope __threadfence = full L2 wb/inv per wave
// (~75-90us/barrier). Here: exchange data moves via relaxed agent-scope atomics
// (write-through, coherence-point visible), so the barrier needs NO cache ops.
// Each wave drains vmcnt at __syncthreads; thread 0 bumps a per-epoch counter
// (one counter per barrier, pre-zeroed, never reset mid-use -> no ordering hazard).
__device__ __forceinline__ void gbar(unsigned* cnt_ep) {
    asm volatile("s_waitcnt vmcnt(0)" ::: "memory");
    __syncthreads();
    if (threadIdx.x == 0) {
        __hip_atomic_fetch_add(cnt_ep, 1u, __ATOMIC_RELAXED,
                               __HIP_MEMORY_SCOPE_AGENT);
        while (__hip_atomic_load(cnt_ep, __ATOMIC_RELAXED,
                                 __HIP_MEMORY_SCOPE_AGENT) < (unsigned)NBLK)
            __builtin_amdgcn_s_sleep(2);
    }
    __syncthreads();
}

union F2U { float2 f; unsigned long long u; };

// Apply gates [seg_lo(SEG), seg_hi(SEG)) to the 8 register amps.
template<int SEG>
__device__ __forceinline__ void do_gates(float (&ar)[8], float (&ai)[8],
    const float (*uc)[8], float* lds_r, float* lds_i, int tid, int hbase)
{
    constexpr int LO = seg_lo(SEG);
    constexpr int HI = seg_hi(SEG);
    #pragma unroll
    for (int g = LO; g < HI; ++g) {
        const int m = TAB.g[g].m, u = TAB.g[g].u;
        const float4 c0 = *(const float4*)&uc[g][0];  // {00r,00i,01r,01i}
        const float4 c1 = *(const float4*)&uc[g][4];  // {10r,10i,11r,11i}
        const bool rb = (__popc(hbase & u) & 1) != 0;
        const float D0r = rb ? c1.z : c0.x, D0i = rb ? c1.w : c0.y;
        const float O0r = rb ? c1.x : c0.z, O0i = rb ? c1.y : c0.w;
        const float D1r = rb ? c0.x : c1.z, D1i = rb ? c0.y : c1.w;
        const float O1r = rb ? c0.z : c1.x, O1i = rb ? c0.w : c1.y;

        const int ml = m & 63;            // lane part
        const int mk = (m >> 6) & 7;      // reg part
        const int mw = (m >> 9) & 7;      // wave part
        float pr[8], pim[8];
        if (mw == 0 && ml == 0) {
            #pragma unroll
            for (int k = 0; k < 8; ++k) { pr[k] = ar[k ^ mk]; pim[k] = ai[k ^ mk]; }
        } else if (mw == 0) {
            #pragma unroll
            for (int k = 0; k < 8; ++k) {
                pr[k]  = __shfl_xor(ar[k ^ mk], ml, 64);
                pim[k] = __shfl_xor(ai[k ^ mk], ml, 64);
            }
        } else {
            const int tm = (mw << 6) | ml;
            __syncthreads();   // WAR: prior readers of lds done
            #pragma unroll
            for (int k = 0; k < 8; ++k) {
                lds_r[k * 512 + tid] = ar[k];
                lds_i[k * 512 + tid] = ai[k];
            }
            __syncthreads();
            #pragma unroll
            for (int k = 0; k < 8; ++k) {
                pr[k]  = lds_r[(k ^ mk) * 512 + (tid ^ tm)];
                pim[k] = lds_i[(k ^ mk) * 512 + (tid ^ tm)];
            }
        }
        const int ku = (u >> 6) & 7;
        #pragma unroll
        for (int k = 0; k < 8; ++k) {
            const int cls = __popc(k & ku) & 1;   // compile-time per k
            const float Dr = cls ? D1r : D0r, Di = cls ? D1i : D0i;
            const float Or = cls ? O1r : O0r, Oi = cls ? O1i : O0i;
            float nr = Dr * ar[k] - Di * ai[k] + Or * pr[k] - Oi * pim[k];
            float ni = Dr * ai[k] + Di * ar[k] + Or * pim[k] + Oi * pr[k];
            ar[k] = nr; ai[k] = ni;
        }
    }
}

// ============ single launch: 256 blocks x 512 threads, fence-free barriers ============
// h = p<<12 | w<<9 | k<<6 | l ;  e = blk>>2, p = blk&3, w = tid>>6, l = tid&63
// Boundary sigma ({12,13}<->{6,7}): amps with (k&3)==p are fixed points (stay in
// registers). Others move, writer slot (k&3)<<12 | w<<9 | (k>>2)<<8 | p<<6 | l,
// via relaxed agent-scope 8B atomics (coherent, no fences). Both sides coalesced.
__global__ void __launch_bounds__(512, 2)
qvc_persist(const float* __restrict__ x, const float* __restrict__ W,
            const float* __restrict__ bias, float2* __restrict__ bufA,
            float2* __restrict__ bufB, float* __restrict__ part,
            float* __restrict__ out, unsigned* __restrict__ bar)
{
    __shared__ __align__(16) float uc[NGATES][8];
    __shared__ float lds_r[8 * 512];
    __shared__ float lds_i[8 * 512];
    __shared__ float red[8][NQ];

    const int blk = blockIdx.x;
    const int e = blk >> 2, p = blk & 3;
    const int tid = threadIdx.x;
    const int w = tid >> 6, l = tid & 63;
    const int hbase = (p << 12) | (w << 9) | l;   // h minus the k bits
    const float* xb = x + e * NPAR;

    // ---- all 70 gate-coefficient sets, one gate per thread ----
    if (tid < NGATES) {
        const int gslot = TAB.g[tid].slot;
        const int layer = gslot / 14, q = gslot % 14;
        const int pidx = (layer < 4) ? layer * 42 + q * 3 : 168 + q * 2;
        float a1 = 0.5f * xb[pidx], a2 = 0.5f * xb[pidx + 1];
        float s1, c1, s2, c2;
        sincosf(a1, &s1, &c1);
        sincosf(a2, &s2, &c2);
        float A00r =  c2 * c1, A00i =  s2 * s1;
        float A01r = -s2 * c1, A01i = -c2 * s1;
        float A10r =  s2 * c1, A10i = -c2 * s1;
        float A11r =  c2 * c1, A11i = -s2 * s1;
        float U0, U1, U2, U3, U4, U5, U6, U7;
        if (layer < 4) {
            float a3 = 0.5f * xb[pidx + 2]; float s3, c3; sincosf(a3, &s3, &c3);
            U0 = c3 * A00r + s3 * A00i; U1 = c3 * A00i - s3 * A00r;
            U2 = c3 * A01r + s3 * A01i; U3 = c3 * A01i - s3 * A01r;
            U4 = c3 * A10r - s3 * A10i; U5 = c3 * A10i + s3 * A10r;
            U6 = c3 * A11r - s3 * A11i; U7 = c3 * A11i + s3 * A11r;
        } else {
            U0 = A00r; U1 = A00i; U2 = A01r; U3 = A01i;
            U4 = A10r; U5 = A10i; U6 = A11r; U7 = A11i;
        }
        uc[tid][0] = U0; uc[tid][1] = U1; uc[tid][2] = U2; uc[tid][3] = U3;
        uc[tid][4] = U4; uc[tid][5] = U5; uc[tid][6] = U6; uc[tid][7] = U7;
    }

    float ar[8], ai[8];
    #pragma unroll
    for (int k = 0; k < 8; ++k) { ar[k] = 0.0f; ai[k] = 0.0f; }
    if (p == 0 && tid == 0) ar[0] = 1.0f;
    __syncthreads();

    // sigma exchange: skip fixed points (k&3)==p; coherent relaxed 8B atomics
    auto store_sigma = [&](float2* buf) {
        #pragma unroll
        for (int k = 0; k < 8; ++k) {
            if ((k & 3) == p) continue;          // fixed point: stays in ar/ai
            const int idx = (e << 14) | ((k & 3) << 12) | (w << 9) |
                            ((k >> 2) << 8) | (p << 6) | l;
            F2U v; v.f = make_float2(ar[k], ai[k]);
            __hip_atomic_store((unsigned long long*)&buf[idx], v.u,
                               __ATOMIC_RELAXED, __HIP_MEMORY_SCOPE_AGENT);
        }
    };
    auto load_linear = [&](const float2* buf) {
        #pragma unroll
        for (int k = 0; k < 8; ++k) {
            if ((k & 3) == p) continue;          // fixed point: already in ar/ai
            F2U v;
            v.u = __hip_atomic_load(
                (const unsigned long long*)&buf[(e << 14) | hbase | (k << 6)],
                __ATOMIC_RELAXED, __HIP_MEMORY_SCOPE_AGENT);
            ar[k] = v.f.x; ai[k] = v.f.y;
        }
    };

    do_gates<0>(ar, ai, uc, lds_r, lds_i, tid, hbase);
    store_sigma(bufA);
    gbar(bar + 0 * 16);
    load_linear(bufA);

    do_gates<1>(ar, ai, uc, lds_r, lds_i, tid, hbase);
    store_sigma(bufB);
    gbar(bar + 1 * 16);
    load_linear(bufB);

    do_gates<2>(ar, ai, uc, lds_r, lds_i, tid, hbase);
    store_sigma(bufA);
    gbar(bar + 2 * 16);
    load_linear(bufA);

    do_gates<3>(ar, ai, uc, lds_r, lds_i, tid, hbase);
    store_sigma(bufB);
    gbar(bar + 3 * 16);
    load_linear(bufB);

    do_gates<4>(ar, ai, uc, lds_r, lds_i, tid, hbase);
    store_sigma(bufA);
    gbar(bar + 4 * 16);
    load_linear(bufA);

    do_gates<5>(ar, ai, uc, lds_r, lds_i, tid, hbase);

    // ---- measurement partials: E_q = sum |amp|^2 * (-1)^parity(h & mu[q]) ----
    {
        float eq[NQ];
        #pragma unroll
        for (int q = 0; q < NQ; ++q) eq[q] = 0.0f;
        #pragma unroll
        for (int k = 0; k < 8; ++k) {
            float p2 = ar[k] * ar[k] + ai[k] * ai[k];
            #pragma unroll
            for (int q = 0; q < NQ; ++q) {
                if (__popc(k & ((TAB.mu[q] >> 6) & 7)) & 1) eq[q] -= p2; else eq[q] += p2;
            }
        }
        #pragma unroll
        for (int q = 0; q < NQ; ++q) {
            float v = (__popc(hbase & TAB.mu[q]) & 1) ? -eq[q] : eq[q];
            #pragma unroll
            for (int off = 32; off > 0; off >>= 1) v += __shfl_down(v, off, 64);
            eq[q] = v;
        }
        if (l == 0) {
            #pragma unroll
            for (int q = 0; q < NQ; ++q) red[w][q] = eq[q];
        }
        __syncthreads();
        if (tid < NQ) {
            float s = 0.0f;
            #pragma unroll
            for (int ww = 0; ww < 8; ++ww) s += red[ww][tid];
            __hip_atomic_store(&part[(e * 4 + p) * NQ + tid], s,
                               __ATOMIC_RELAXED, __HIP_MEMORY_SCOPE_AGENT);
        }
    }
    gbar(bar + 5 * 16);

    // ---- head: blocks 0..63, one element each (coherent part reads) ----
    if (blk < 64 && tid < NCLS) {
        const int e2 = blk, c = tid;
        float acc = bias[c];
        const float* pe = part + e2 * 4 * NQ;
        #pragma unroll
        for (int q = 0; q < NQ; ++q) {
            float eqv = 0.0f;
            #pragma unroll
            for (int pp = 0; pp < 4; ++pp)
                eqv += __hip_atomic_load(&pe[pp * NQ + q], __ATOMIC_RELAXED,
                                         __HIP_MEMORY_SCOPE_AGENT);
            acc += W[c * NQ + q] * eqv;
        }
        out[e2 * NCLS + c] = acc;
    }
}

extern "C" void kernel_launch(void* const* d_in, const int* in_sizes, int n_in,
                              void* d_out, int out_size, void* d_ws, size_t ws_size,
                              hipStream_t stream)
{
    const float* x    = (const float*)d_in[0];   // (64, 196)
    const float* W    = (const float*)d_in[1];   // (10, 14)
    const float* bias = (const float*)d_in[2];   // (10,)
    float*       out  = (float*)d_out;           // (64, 10)

    const size_t state_elems = (size_t)64 * DIM;          // float2 each
    float2*   bufA = (float2*)d_ws;
    float2*   bufB = bufA + state_elems;
    float*    part = (float*)(bufB + state_elems);        // 64*4*14 floats
    unsigned* bar  = (unsigned*)((char*)d_ws + 2 * state_elems * sizeof(float2) + 16384);
    (void)ws_size;  // observed 268 MB >> ~16.1 MB needed

    // zero the 6 per-epoch barrier counters every call (graph memset node)
    hipMemsetAsync(bar, 0, 512, stream);

    void* args[] = { (void*)&x, (void*)&W, (void*)&bias,
                     (void*)&bufA, (void*)&bufB, (void*)&part,
                     (void*)&out, (void*)&bar };
    hipLaunchCooperativeKernel((void*)qvc_persist, dim3(NBLK), dim3(512),
                               args, 0, stream);
}